// Round 6
// baseline (249.556 us; speedup 1.0000x reference)
//
#include <hip/hip_runtime.h>
#include <hip/hip_cooperative_groups.h>

namespace cg = cooperative_groups;

// LJ pair energy -> segment-sum onto first atom of each pair, no device atomics.
// Round-6: single COOPERATIVE kernel (3 phases, 2 grid.sync()) to kill the two
// graph-node boundaries and make the true kernel time visible in rocprof.
//   Phase A (bin): per 6144-pair chunk: q = round(half_en(d)*2^15) (23b clamp),
//     bucket = atom>>9 (512 atoms/bucket, nb=196). rank = LDS atomicAdd;
//     4-wave shfl scan -> offs; records (q<<9|local) grouped in LDS; uint4
//     coalesced region write + offset row goffs[b][c].
//   Phase B (reduce): virtual block (s,b): preload lo/hi offset rows to LDS;
//     each wave gathers TWO ~31-record runs at once (lane-split 2x32) to halve
//     the dependent load->LDS-atomic chain; acc[512] ints; write partial[s].
//   Phase C: out[a] = (sum_{s<8} partial[s][a]) * 2^-15.
// Integer accumulation => bit-deterministic output across graph replays.
//
// half_en(d) = 2*((1/d)^12 - (1/d)^6) - e0/2, e0/2 = -2.739720872119788e-3.
// |half_en| <= 21.5 for d >= 0.8 -> |q| <= ~705k < 2^22 (23-bit signed field).

#define CHUNK 6144
#define T1 256
#define NGRP 6               // 6 groups of 4 pairs = 24 pairs/thread
#define ABITS 9
#define APB 512              // atoms per bucket
#define NBMAX 255
#define QSCALE 32768.0f      // 2^15
#define QINV (1.0f / 32768.0f)
#define NS 8                 // reduce slices
#define MAXCPS 256

static __device__ __forceinline__ float half_en(float d) {
    const float half_e0 = -2.739720872119788e-3f;
    float inv = 1.0f / d;
    float i2 = inv * inv;
    float i6 = i2 * i2 * i2;
    return 2.0f * (i6 * i6 - i6) - half_e0;
}

static __device__ __forceinline__ int quant(float e) {
    int q = __float2int_rn(e * QSCALE);
    return max(-4194304, min(4194303, q));  // 23-bit signed
}

struct SmemA {
    unsigned recs[CHUNK];
    unsigned cnt[256];
    unsigned offs[256];
    unsigned wsum[4];
};
struct SmemB {
    int acc[APB];
    unsigned lo[MAXCPS];
    unsigned hi[MAXCPS];
};

// ---- Phase A body: bin one chunk ----
static __device__ __forceinline__ void phaseA_chunk(SmemA& sm,
                                                    const float* __restrict__ dist,
                                                    const int* __restrict__ ind2,
                                                    unsigned* __restrict__ grec,
                                                    unsigned* __restrict__ goffs,
                                                    int n_pairs, int nchunk, int nb, int c) {
    const int t = threadIdx.x;
    const int base = c * CHUNK;

    __syncthreads();          // protect recs/cnt reuse across chunk iterations
    sm.cnt[t] = 0;
    __syncthreads();

    unsigned rec[NGRP * 4];
    unsigned br[NGRP * 4];    // (bucket<<16) | rank ; 0xFFFFFFFF = invalid

    #pragma unroll
    for (int g = 0; g < NGRP; ++g) {
        const int p0 = base + g * (T1 * 4) + t * 4;
        float dd[4] = {0.f, 0.f, 0.f, 0.f};
        int ii[4] = {0, 0, 0, 0};
        if (p0 + 4 <= n_pairs) {
            float4 d = *reinterpret_cast<const float4*>(dist + p0);
            int4 ia = *reinterpret_cast<const int4*>(ind2 + 2 * p0);
            int4 ib = *reinterpret_cast<const int4*>(ind2 + 2 * p0 + 4);
            dd[0] = d.x; dd[1] = d.y; dd[2] = d.z; dd[3] = d.w;
            ii[0] = ia.x; ii[1] = ia.z; ii[2] = ib.x; ii[3] = ib.z;
        } else {
            #pragma unroll
            for (int k = 0; k < 4; ++k)
                if (p0 + k < n_pairs) { dd[k] = dist[p0 + k]; ii[k] = ind2[2 * (p0 + k)]; }
        }
        #pragma unroll
        for (int k = 0; k < 4; ++k) {
            const int j = g * 4 + k;
            if (p0 + k < n_pairs) {
                const int id = ii[k];
                const int b = id >> ABITS;
                const int q = quant(half_en(dd[k]));
                rec[j] = (((unsigned)q) << ABITS) | (unsigned)(id & (APB - 1));
                const unsigned rank = atomicAdd(&sm.cnt[b], 1u);  // rank in bucket
                br[j] = ((unsigned)b << 16) | rank;               // rank < 6144
            } else {
                br[j] = 0xFFFFFFFFu;
                rec[j] = 0;
            }
        }
    }
    __syncthreads();

    // Exclusive scan of cnt[0..255]: per-wave shfl scan + wave-total fixup.
    {
        const unsigned v = sm.cnt[t];
        unsigned inc = v;
        #pragma unroll
        for (int d = 1; d < 64; d <<= 1) {
            const unsigned x = __shfl_up(inc, d, 64);
            if ((t & 63) >= d) inc += x;
        }
        if ((t & 63) == 63) sm.wsum[t >> 6] = inc;
        __syncthreads();
        unsigned add = 0;
        #pragma unroll
        for (int j = 0; j < 4; ++j)
            if (j < (t >> 6)) add += sm.wsum[j];
        sm.offs[t] = add + inc - v;  // exclusive
    }
    __syncthreads();

    // Place records grouped by bucket (rank trick, single atomic round).
    #pragma unroll
    for (int j = 0; j < NGRP * 4; ++j) {
        if (br[j] != 0xFFFFFFFFu) {
            const unsigned pos = sm.offs[br[j] >> 16] + (br[j] & 0xFFFFu);
            sm.recs[pos] = rec[j];
        }
    }
    __syncthreads();

    const int nv = min(CHUNK, n_pairs - base);
    for (int i4 = t * 4; i4 + 4 <= nv; i4 += T1 * 4) {
        uint4 v = *reinterpret_cast<const uint4*>(&sm.recs[i4]);
        *reinterpret_cast<uint4*>(&grec[(size_t)base + i4]) = v;
    }
    for (int i = (nv & ~3) + t; i < nv; i += T1)
        grec[(size_t)base + i] = sm.recs[i];
    if (t <= nb)
        goffs[(size_t)t * nchunk + c] = sm.offs[t];  // row nb = end sentinel (=nv)
}

// ---- Phase B body: reduce one (slice s, bucket b) ----
static __device__ __forceinline__ void phaseB_vb(SmemB& sm,
                                                 const unsigned* __restrict__ grec,
                                                 const unsigned* __restrict__ goffs,
                                                 int* __restrict__ partial,
                                                 int nchunk, int nb, int natom_pad,
                                                 int cps, int vb) {
    const int t = threadIdx.x;
    const int b = vb % nb;
    const int s = vb / nb;

    __syncthreads();          // protect acc/lo/hi reuse across vb iterations
    #pragma unroll
    for (int k = 0; k < APB / T1; ++k) sm.acc[t + k * T1] = 0;

    const int c0 = s * cps;
    const int cn = min(nchunk - c0, cps);
    if (cn > 0) {
        const unsigned* r0 = goffs + (size_t)b * nchunk + c0;
        const unsigned* r1 = goffs + (size_t)(b + 1) * nchunk + c0;
        for (int i = t; i < cn; i += T1) { sm.lo[i] = r0[i]; sm.hi[i] = r1[i]; }
    }
    __syncthreads();

    if (cn > 0) {
        // Each wave handles TWO runs at once: lanes 0-31 -> run cc+0,
        // lanes 32-63 -> run cc+1 (runs avg ~31 records; halves dep chain).
        const int wv = t >> 6;
        const int half = (t >> 5) & 1;
        const int sub = t & 31;
        for (int cc = wv * 2; cc < cn; cc += (T1 / 64) * 2) {
            const int myrun = cc + half;
            if (myrun < cn) {
                const unsigned o0 = sm.lo[myrun];
                const unsigned o1 = sm.hi[myrun];
                const size_t rb = (size_t)(c0 + myrun) * CHUNK;
                for (unsigned i = o0 + sub; i < o1; i += 32) {
                    const unsigned r = grec[rb + i];
                    atomicAdd(&sm.acc[r & (APB - 1)], ((int)r) >> ABITS);
                }
            }
        }
    }
    __syncthreads();

    int* dst = partial + (size_t)s * natom_pad + (size_t)b * APB;
    #pragma unroll
    for (int k = 0; k < APB / T1; ++k) dst[t + k * T1] = sm.acc[t + k * T1];
}

// ---- Fused cooperative kernel ----
__global__ __launch_bounds__(T1, 4) void lj_fused(const float* __restrict__ dist,
                                                  const int* __restrict__ ind2,
                                                  unsigned* __restrict__ grec,
                                                  unsigned* __restrict__ goffs,
                                                  int* __restrict__ partial,
                                                  float* __restrict__ out,
                                                  int n_pairs, int natom, int nchunk,
                                                  int nb, int natom_pad, int cps) {
    __shared__ union { SmemA a; SmemB b; } sm;

    const int bid = blockIdx.x;
    const int grid = gridDim.x;

    for (int c = bid; c < nchunk; c += grid)
        phaseA_chunk(sm.a, dist, ind2, grec, goffs, n_pairs, nchunk, nb, c);

    cg::this_grid().sync();

    for (int vb = bid; vb < NS * nb; vb += grid)
        phaseB_vb(sm.b, grec, goffs, partial, nchunk, nb, natom_pad, cps, vb);

    cg::this_grid().sync();

    for (int a = bid * T1 + threadIdx.x; a < natom; a += grid * T1) {
        int ssum = 0;
        #pragma unroll
        for (int s = 0; s < NS; ++s)
            ssum += partial[(size_t)s * natom_pad + a];
        out[a] = (float)ssum * QINV;
    }
}

// ---- Fallback: same phases as 3 separate kernels (no cooperative launch) ----
__global__ __launch_bounds__(T1, 4) void lj_bin_k(const float* __restrict__ dist,
                                                  const int* __restrict__ ind2,
                                                  unsigned* __restrict__ grec,
                                                  unsigned* __restrict__ goffs,
                                                  int n_pairs, int nchunk, int nb) {
    __shared__ SmemA sm;
    for (int c = blockIdx.x; c < nchunk; c += gridDim.x)
        phaseA_chunk(sm, dist, ind2, grec, goffs, n_pairs, nchunk, nb, c);
}

__global__ __launch_bounds__(T1, 4) void lj_red_k(const unsigned* __restrict__ grec,
                                                  const unsigned* __restrict__ goffs,
                                                  int* __restrict__ partial,
                                                  int nchunk, int nb, int natom_pad, int cps) {
    __shared__ SmemB sm;
    for (int vb = blockIdx.x; vb < NS * nb; vb += gridDim.x)
        phaseB_vb(sm, grec, goffs, partial, nchunk, nb, natom_pad, cps, vb);
}

__global__ void lj_fin_k(const int* __restrict__ partial, float* __restrict__ out,
                         int natom, int natom_pad) {
    const int a = blockIdx.x * blockDim.x + threadIdx.x;
    if (a >= natom) return;
    int ssum = 0;
    #pragma unroll
    for (int s = 0; s < NS; ++s)
        ssum += partial[(size_t)s * natom_pad + a];
    out[a] = (float)ssum * QINV;
}

// Last-resort fallback: direct device atomics.
__global__ void lj_scatter_direct(const float* __restrict__ dist,
                                  const int* __restrict__ ind2,
                                  float* __restrict__ out,
                                  int n_pairs) {
    int t = blockIdx.x * blockDim.x + threadIdx.x;
    int i = t * 4;
    if (i >= n_pairs) return;
    if (i + 4 <= n_pairs) {
        float4 d = *reinterpret_cast<const float4*>(dist + i);
        int4 ia = *reinterpret_cast<const int4*>(ind2 + 2 * i);
        int4 ib = *reinterpret_cast<const int4*>(ind2 + 2 * i + 4);
        atomicAdd(&out[ia.x], half_en(d.x));
        atomicAdd(&out[ia.z], half_en(d.y));
        atomicAdd(&out[ib.x], half_en(d.z));
        atomicAdd(&out[ib.z], half_en(d.w));
    } else {
        for (int p = i; p < n_pairs; ++p)
            atomicAdd(&out[ind2[2 * p]], half_en(dist[p]));
    }
}

extern "C" void kernel_launch(void* const* d_in, const int* in_sizes, int n_in,
                              void* d_out, int out_size, void* d_ws, size_t ws_size,
                              hipStream_t stream) {
    const float* dist = (const float*)d_in[0];
    // d_in[1] = ind_1: only its shape (natom == out_size) matters.
    const int* ind2 = (const int*)d_in[2];
    float* out = (float*)d_out;

    const int n_pairs = in_sizes[0];
    const int natom = out_size;

    const int nchunk = (n_pairs + CHUNK - 1) / CHUNK;
    const int nb = (natom + APB - 1) / APB;
    const int natom_pad = nb * APB;
    const int cps = (nchunk + NS - 1) / NS;

    const size_t rec_bytes = (size_t)nchunk * CHUNK * sizeof(unsigned);
    const size_t offs_bytes = (size_t)(nb + 1) * nchunk * sizeof(unsigned);
    const size_t part_bytes = (size_t)NS * natom_pad * sizeof(int);
    const size_t need = rec_bytes + offs_bytes + part_bytes;

    if (nb + 1 > 256 || cps > MAXCPS || need > ws_size) {
        hipMemsetAsync(d_out, 0, (size_t)out_size * sizeof(float), stream);
        int n_threads = (n_pairs + 3) / 4;
        int grid = (n_threads + 255) / 256;
        lj_scatter_direct<<<grid, 256, 0, stream>>>(dist, ind2, out, n_pairs);
        return;
    }

    unsigned* grec = (unsigned*)d_ws;
    unsigned* goffs = (unsigned*)((char*)d_ws + rec_bytes);
    int* partial = (int*)((char*)d_ws + rec_bytes + offs_bytes);

    // Cooperative path: query support + co-residency every call (deterministic).
    int dev = 0;
    hipGetDevice(&dev);
    int coop = 0, numCU = 0;
    hipDeviceGetAttribute(&coop, hipDeviceAttributeCooperativeLaunch, dev);
    hipDeviceGetAttribute(&numCU, hipDeviceAttributeMultiprocessorCount, dev);
    int maxB = 0;
    hipOccupancyMaxActiveBlocksPerMultiprocessor(&maxB, lj_fused, T1, 0);

    if (coop && maxB > 0 && numCU > 0) {
        int grid = maxB * numCU;
        if (grid > NS * nb) grid = NS * nb;
        int np = n_pairs, na = natom, nc = nchunk, nbb = nb, npad = natom_pad, cp = cps;
        void* args[] = {(void*)&dist, (void*)&ind2, (void*)&grec, (void*)&goffs,
                        (void*)&partial, (void*)&out, (void*)&np, (void*)&na,
                        (void*)&nc, (void*)&nbb, (void*)&npad, (void*)&cp};
        hipError_t e = hipLaunchCooperativeKernel((const void*)lj_fused, dim3(grid),
                                                  dim3(T1), args, 0, stream);
        if (e == hipSuccess) return;
    }

    // Non-cooperative fallback: same phases, 3 dispatches.
    lj_bin_k<<<nchunk, T1, 0, stream>>>(dist, ind2, grec, goffs, n_pairs, nchunk, nb);
    lj_red_k<<<NS * nb, T1, 0, stream>>>(grec, goffs, partial, nchunk, nb, natom_pad, cps);
    int fgrid = (natom + 255) / 256;
    lj_fin_k<<<fgrid, 256, 0, stream>>>(partial, out, natom, natom_pad);
}

// Round 7
// 40.296 us; speedup vs baseline: 6.1931x; 6.1931x over previous
//
#include <hip/hip_runtime.h>

// LJ pair energy -> segment-sum onto first atom of each pair, no device atomics.
// Round-7: round-5 3-kernel pipeline + XCD-local record striping.
//   K1 lj_bin (512 thr, CHUNK=8192): q = round(half_en(d)*2^15) (23b clamp),
//      bucket = atom>>9 (512 atoms/bucket, nb=196). rank = LDS atomicAdd;
//      shfl scan -> offs; records (q<<9|local) grouped in LDS; uint4 coalesced
//      region write; offset row in TRANSPOSED layout goffs[(b*8+s)*P + c/8],
//      s = c%8.
//   K2 lj_bucket_reduce (grid vb = b*8+s): slice s owns chunks c≡s (mod 8).
//      With default round-robin blockIdx->XCD, reducer (vb%8 = s) lands on the
//      SAME XCD whose L2 holds those chunks' records => record round-trip is
//      L2-local. Preload contiguous lo/hi offset rows; 2x32 lane-split run
//      gather; LDS int acc[512]; write partial[s].
//   K3 lj_final: out[a] = (sum_{s<8} partial[s][a]) * 2^-15.
// Integer accumulation => bit-deterministic output across graph replays.
//
// half_en(d) = 2*((1/d)^12 - (1/d)^6) - e0/2, e0/2 = -2.739720872119788e-3.
// |half_en| <= ~23.3 for d >= 0.8 -> |q| <= ~764k < 2^22 (23-bit signed field).

#define CHUNK 8192
#define T1 512
#define ABITS 9
#define APB 512             // atoms per bucket
#define QSCALE 32768.0f     // 2^15
#define QINV (1.0f / 32768.0f)
#define NS 8                // slices == XCD count
#define MAXCPS 160          // max chunks per slice (P)

static __device__ __forceinline__ float half_en(float d) {
    const float half_e0 = -2.739720872119788e-3f;
    float inv = 1.0f / d;
    float i2 = inv * inv;
    float i6 = i2 * i2 * i2;
    return 2.0f * (i6 * i6 - i6) - half_e0;
}

static __device__ __forceinline__ int quant(float e) {
    int q = __float2int_rn(e * QSCALE);
    return max(-4194304, min(4194303, q));  // 23-bit signed
}

__global__ __launch_bounds__(T1) void lj_bin(const float* __restrict__ dist,
                                             const int* __restrict__ ind2,
                                             unsigned* __restrict__ grec,
                                             unsigned* __restrict__ goffs,
                                             int n_pairs, int nchunk, int nb, int P) {
    __shared__ unsigned cnt[256];
    __shared__ unsigned offs[256];
    __shared__ unsigned wsum[8];
    __shared__ unsigned recs[CHUNK];

    const int t = threadIdx.x;
    const int c = blockIdx.x;
    const int base = c * CHUNK;

    if (t < 256) cnt[t] = 0;
    __syncthreads();

    unsigned rec[16];
    unsigned br[16];  // (bucket<<16) | rank ; 0xFFFFFFFF = invalid

    #pragma unroll
    for (int g = 0; g < 4; ++g) {
        const int p0 = base + g * (T1 * 4) + t * 4;
        float dd[4] = {0.f, 0.f, 0.f, 0.f};
        int ii[4] = {0, 0, 0, 0};
        if (p0 + 4 <= n_pairs) {
            float4 d = *reinterpret_cast<const float4*>(dist + p0);
            int4 ia = *reinterpret_cast<const int4*>(ind2 + 2 * p0);
            int4 ib = *reinterpret_cast<const int4*>(ind2 + 2 * p0 + 4);
            dd[0] = d.x; dd[1] = d.y; dd[2] = d.z; dd[3] = d.w;
            ii[0] = ia.x; ii[1] = ia.z; ii[2] = ib.x; ii[3] = ib.z;
        } else {
            #pragma unroll
            for (int k = 0; k < 4; ++k)
                if (p0 + k < n_pairs) { dd[k] = dist[p0 + k]; ii[k] = ind2[2 * (p0 + k)]; }
        }
        #pragma unroll
        for (int k = 0; k < 4; ++k) {
            const int j = g * 4 + k;
            if (p0 + k < n_pairs) {
                const int id = ii[k];
                const int b = id >> ABITS;
                const int q = quant(half_en(dd[k]));
                rec[j] = (((unsigned)q) << ABITS) | (unsigned)(id & (APB - 1));
                const unsigned rank = atomicAdd(&cnt[b], 1u);  // rank within bucket
                br[j] = ((unsigned)b << 16) | rank;            // rank < 8192 fits
            } else {
                br[j] = 0xFFFFFFFFu;
                rec[j] = 0;
            }
        }
    }
    __syncthreads();

    // Exclusive scan of cnt[0..255]: per-wave shfl scan + wave-total fixup.
    {
        const unsigned v = (t < 256) ? cnt[t] : 0u;
        unsigned inc = v;
        #pragma unroll
        for (int d = 1; d < 64; d <<= 1) {
            const unsigned x = __shfl_up(inc, d, 64);
            if ((t & 63) >= d) inc += x;
        }
        if (t < 256 && (t & 63) == 63) wsum[t >> 6] = inc;
        __syncthreads();
        if (t < 256) {
            unsigned add = 0;
            #pragma unroll
            for (int j = 0; j < 4; ++j)
                if (j < (t >> 6)) add += wsum[j];
            offs[t] = add + inc - v;  // exclusive
        }
    }
    __syncthreads();

    // Place records grouped by bucket (rank trick, single atomic round).
    #pragma unroll
    for (int j = 0; j < 16; ++j) {
        if (br[j] != 0xFFFFFFFFu) {
            const unsigned pos = offs[br[j] >> 16] + (br[j] & 0xFFFFu);
            recs[pos] = rec[j];
        }
    }
    __syncthreads();

    const int nv = min(CHUNK, n_pairs - base);
    for (int i4 = t * 4; i4 + 4 <= nv; i4 += T1 * 4) {
        uint4 v = *reinterpret_cast<const uint4*>(&recs[i4]);
        *reinterpret_cast<uint4*>(&grec[(size_t)base + i4]) = v;
    }
    for (int i = (nv & ~3) + t; i < nv; i += T1)
        grec[(size_t)base + i] = recs[i];
    // Transposed offset write: row (bucket t, slice s=c%NS), column cc=c/NS.
    // Row nb is the end sentinel (offs[nb] = nv since cnt[b>=nb]=0).
    if (t <= nb)
        goffs[((size_t)t * NS + (c & (NS - 1))) * P + (c >> 3)] = offs[t];
}

#define T2 256

__global__ __launch_bounds__(T2) void lj_bucket_reduce(const unsigned* __restrict__ grec,
                                                       const unsigned* __restrict__ goffs,
                                                       int* __restrict__ partial,
                                                       int nchunk, int nb, int natom_pad,
                                                       int P) {
    __shared__ int acc[APB];
    __shared__ unsigned lo[MAXCPS];
    __shared__ unsigned hi[MAXCPS];

    const int t = threadIdx.x;
    const int vb = blockIdx.x;
    const int s = vb & (NS - 1);   // slice -> same XCD as its chunks (heuristic)
    const int b = vb >> 3;         // NS == 8

    #pragma unroll
    for (int k = 0; k < APB / T2; ++k) acc[t + k * T2] = 0;

    // Slice s owns chunks c = s + NS*cc, cc in [0, cn).
    const int cn = (nchunk - s + NS - 1) >> 3;
    if (cn > 0) {
        const unsigned* r0 = goffs + ((size_t)b * NS + s) * P;
        const unsigned* r1 = goffs + ((size_t)(b + 1) * NS + s) * P;
        for (int i = t; i < cn; i += T2) { lo[i] = r0[i]; hi[i] = r1[i]; }
    }
    __syncthreads();

    if (cn > 0) {
        // Each wave handles TWO runs at once (lanes 0-31 / 32-63).
        const int wv = t >> 6;
        const int half = (t >> 5) & 1;
        const int sub = t & 31;
        for (int cc = wv * 2; cc < cn; cc += (T2 / 64) * 2) {
            const int myrun = cc + half;
            if (myrun < cn) {
                const unsigned o0 = lo[myrun];
                const unsigned o1 = hi[myrun];
                const size_t rb = (size_t)(s + myrun * NS) * CHUNK;
                for (unsigned i = o0 + sub; i < o1; i += 32) {
                    const unsigned r = grec[rb + i];
                    atomicAdd(&acc[r & (APB - 1)], ((int)r) >> ABITS);
                }
            }
        }
    }
    __syncthreads();

    int* dst = partial + (size_t)s * natom_pad + (size_t)b * APB;
    #pragma unroll
    for (int k = 0; k < APB / T2; ++k) dst[t + k * T2] = acc[t + k * T2];
}

__global__ void lj_final(const int* __restrict__ partial, float* __restrict__ out,
                         int natom, int natom_pad) {
    const int a = blockIdx.x * blockDim.x + threadIdx.x;
    if (a >= natom) return;
    int ssum = 0;
    #pragma unroll
    for (int s = 0; s < NS; ++s)
        ssum += partial[(size_t)s * natom_pad + a];
    out[a] = (float)ssum * QINV;
}

// Fallback: direct device atomics if ws too small / shape unexpected.
__global__ void lj_scatter_direct(const float* __restrict__ dist,
                                  const int* __restrict__ ind2,
                                  float* __restrict__ out,
                                  int n_pairs) {
    int t = blockIdx.x * blockDim.x + threadIdx.x;
    int i = t * 4;
    if (i >= n_pairs) return;
    if (i + 4 <= n_pairs) {
        float4 d = *reinterpret_cast<const float4*>(dist + i);
        int4 ia = *reinterpret_cast<const int4*>(ind2 + 2 * i);
        int4 ib = *reinterpret_cast<const int4*>(ind2 + 2 * i + 4);
        atomicAdd(&out[ia.x], half_en(d.x));
        atomicAdd(&out[ia.z], half_en(d.y));
        atomicAdd(&out[ib.x], half_en(d.z));
        atomicAdd(&out[ib.z], half_en(d.w));
    } else {
        for (int p = i; p < n_pairs; ++p)
            atomicAdd(&out[ind2[2 * p]], half_en(dist[p]));
    }
}

extern "C" void kernel_launch(void* const* d_in, const int* in_sizes, int n_in,
                              void* d_out, int out_size, void* d_ws, size_t ws_size,
                              hipStream_t stream) {
    const float* dist = (const float*)d_in[0];
    // d_in[1] = ind_1: only its shape (natom == out_size) matters.
    const int* ind2 = (const int*)d_in[2];
    float* out = (float*)d_out;

    const int n_pairs = in_sizes[0];
    const int natom = out_size;

    const int nchunk = (n_pairs + CHUNK - 1) / CHUNK;
    const int nb = (natom + APB - 1) / APB;
    const int natom_pad = nb * APB;
    const int P = (nchunk + NS - 1) / NS;   // max chunks per slice

    const size_t rec_bytes = (size_t)nchunk * CHUNK * sizeof(unsigned);
    const size_t offs_bytes = (size_t)(nb + 1) * NS * P * sizeof(unsigned);
    const size_t part_bytes = (size_t)NS * natom_pad * sizeof(int);
    const size_t need = rec_bytes + offs_bytes + part_bytes;

    if (nb + 1 > 256 || P > MAXCPS || need > ws_size) {
        hipMemsetAsync(d_out, 0, (size_t)out_size * sizeof(float), stream);
        int n_threads = (n_pairs + 3) / 4;
        int grid = (n_threads + 255) / 256;
        lj_scatter_direct<<<grid, 256, 0, stream>>>(dist, ind2, out, n_pairs);
        return;
    }

    unsigned* grec = (unsigned*)d_ws;
    unsigned* goffs = (unsigned*)((char*)d_ws + rec_bytes);
    int* partial = (int*)((char*)d_ws + rec_bytes + offs_bytes);

    lj_bin<<<nchunk, T1, 0, stream>>>(dist, ind2, grec, goffs, n_pairs, nchunk, nb, P);
    lj_bucket_reduce<<<NS * nb, T2, 0, stream>>>(grec, goffs, partial,
                                                 nchunk, nb, natom_pad, P);
    int fgrid = (natom + 255) / 256;
    lj_final<<<fgrid, 256, 0, stream>>>(partial, out, natom, natom_pad);
}